// Round 3
// baseline (109.863 us; speedup 1.0000x reference)
//
#include <hip/hip_runtime.h>

// CompactBilinearPooling: count-sketch + circular conv via FFT (B=256, D=4096, N=16384).
// R3: wave-local middle FFT. Pass A (stride 1024, cross-wave) + wave-local
// 1024-pt FFT per chunk: alpha (m=512..64) in regs, wave-private LDS exchange
// (s_waitcnt only, no barrier), beta (m=32..4) in regs, gamma (m=2,1) via DPP
// quad_perm butterflies (VALU pipe, no LDS). 6 barriers vs 9.
// LDS layout: XOR swizzle slot = e ^ ((e>>4)&15) — all access patterns at the
// 4-words/bank b64 minimum; exact 128 KB.

#define FFT_N   16384
#define LOGN    14
#define BLOCK   1024
#define DIM     4096
#define SLOT(e) ((e) ^ (((e) >> 4) & 15))

__device__ __forceinline__ float2 cmul(float2 a, float2 b) {
    return make_float2(a.x * b.x - a.y * b.y, a.x * b.y + a.y * b.x);
}
__device__ __forceinline__ float2 csqr(float2 a) {
    return make_float2(a.x * a.x - a.y * a.y, 2.f * a.x * a.y);
}

template<int CTRL>
__device__ __forceinline__ float2 dpp2(float2 v) {
    float2 o;
    o.x = __int_as_float(__builtin_amdgcn_update_dpp(0, __float_as_int(v.x), CTRL, 0xF, 0xF, false));
    o.y = __int_as_float(__builtin_amdgcn_update_dpp(0, __float_as_int(v.y), CTRL, 0xF, 0xF, false));
    return o;
}
#define DPP_XOR1 0xB1   // quad_perm [1,0,3,2]
#define DPP_XOR2 0x4E   // quad_perm [2,3,0,1]

#define DECL_TW_TABLES \
    const float CT[8] = {1.f, 0.92387953f, 0.70710678f, 0.38268343f, 0.f, -0.38268343f, -0.70710678f, -0.92387953f}; \
    const float ST[8] = {0.f, 0.38268343f, 0.70710678f, 0.92387953f, 1.f, 0.92387953f, 0.70710678f, 0.38268343f};

// Forward DIF, 4 stages over the register index (verified in R2).
// Stage p: butterfly twiddle T = W[p] * exp(-i*pi*jp/2^p), W[3]=exp(i*phi).
__device__ __forceinline__ void fft16_dif(float2* r, float phi) {
    DECL_TW_TABLES
    float2 W[4];
    __sincosf(phi, &W[3].y, &W[3].x);
    W[2] = csqr(W[3]); W[1] = csqr(W[2]); W[0] = csqr(W[1]);
    #pragma unroll
    for (int p = 3; p >= 0; --p) {
        #pragma unroll
        for (int h = 0; h < 8; ++h) {
            const int jp = h & ((1 << p) - 1);
            const int j  = ((h >> p) << (p + 1)) | jp;
            const int ci = jp << (3 - p);
            const float2 T = cmul(W[p], make_float2(CT[ci], -ST[ci]));
            float2 a = r[j], b = r[j + (1 << p)];
            r[j] = make_float2(a.x + b.x, a.y + b.y);
            float2 d = make_float2(a.x - b.x, a.y - b.y);
            r[j + (1 << p)] = cmul(d, T);
        }
    }
}

// Inverse DIT, 4 stages (verified in R2). T = W[p] * exp(+i*pi*jp/2^p).
__device__ __forceinline__ void fft16_dit(float2* r, float phi) {
    DECL_TW_TABLES
    float2 W[4];
    __sincosf(phi, &W[3].y, &W[3].x);
    W[2] = csqr(W[3]); W[1] = csqr(W[2]); W[0] = csqr(W[1]);
    #pragma unroll
    for (int p = 0; p <= 3; ++p) {
        #pragma unroll
        for (int h = 0; h < 8; ++h) {
            const int jp = h & ((1 << p) - 1);
            const int j  = ((h >> p) << (p + 1)) | jp;
            const int ci = jp << (3 - p);
            const float2 T = cmul(W[p], make_float2(CT[ci], ST[ci]));
            float2 a = r[j];
            float2 b = cmul(r[j + (1 << p)], T);
            r[j]            = make_float2(a.x + b.x, a.y + b.y);
            r[j + (1 << p)] = make_float2(a.x - b.x, a.y - b.y);
        }
    }
}

__launch_bounds__(BLOCK)
__global__ void cbp_fft_kernel(const float* __restrict__ x1,
                               const float* __restrict__ x2,
                               const int* __restrict__ h1,
                               const float* __restrict__ s1,
                               float* __restrict__ out) {
    __shared__ float2 zz[FFT_N];   // 128 KB, XOR-swizzled addressing
    const int tid = threadIdx.x;
    const int l   = tid & 63;     // lane
    const int w   = tid >> 6;     // wave = chunk index
    const int b   = blockIdx.x;

    // ---- zero sketch ----
    #pragma unroll
    for (int j = 0; j < 16; ++j) zz[tid + (j << 10)] = make_float2(0.f, 0.f);
    __syncthreads();

    // ---- count-sketch scatter ----
    const float* x1r = x1 + (size_t)b * DIM;
    const float* x2r = x2 + (size_t)b * DIM;
    #pragma unroll
    for (int i = 0; i < DIM / BLOCK; ++i) {
        int d = tid + i * BLOCK;
        float s = s1[d];
        int   h = h1[d];
        atomicAdd(&zz[SLOT(h)].x, s * x1r[d]);
        atomicAdd(&zz[SLOT(h)].y, s * x2r[d]);
    }
    __syncthreads();

    float2 r[16];
    const int W  = w << 10;                               // chunk base
    const int cb = W + (l & 3) + ((l >> 2) << 6);         // cluster base (Lbeta)

    // ======== fwd pass A: m=8192..1024 (stride 1024, cross-wave) ========
    #pragma unroll
    for (int j = 0; j < 16; ++j) r[j] = zz[SLOT(tid + (j << 10))];
    fft16_dif(r, (float)tid * (-3.14159265358979323846f / 8192.f));
    #pragma unroll
    for (int j = 0; j < 16; ++j) zz[SLOT(tid + (j << 10))] = r[j];
    __syncthreads();

    // ======== fwd wave-local 1024-pt FFT on chunk w ========
    // alpha: m=512..64, layout e = l + j*64
    #pragma unroll
    for (int j = 0; j < 16; ++j) r[j] = zz[SLOT(W + l + (j << 6))];
    fft16_dif(r, (float)l * (-3.14159265358979323846f / 512.f));
    #pragma unroll
    for (int j = 0; j < 16; ++j) zz[SLOT(W + l + (j << 6))] = r[j];
    __asm__ volatile("s_waitcnt lgkmcnt(0)" ::: "memory");   // wave-private exchange
    // beta: m=32..4, layout e = (l&3) + j*4 + (l>>2)*64
    #pragma unroll
    for (int j = 0; j < 16; ++j) r[j] = zz[SLOT(cb + (j << 2))];
    fft16_dif(r, (float)(l & 3) * (-3.14159265358979323846f / 32.f));
    // gamma: m=2 then m=1 via DPP (partner lanes l^2, l^1; e&3 == l&3)
    {
        const float s2  = (l & 2) ? -1.f : 1.f;
        const bool  hiT = ((l & 3) == 3);   // upper lane with k=1: T = -i
        #pragma unroll
        for (int j = 0; j < 16; ++j) {
            float2 v = dpp2<DPP_XOR2>(r[j]);
            float dx = fmaf(s2, r[j].x, v.x);   // lower: a+b ; upper: a-b
            float dy = fmaf(s2, r[j].y, v.y);
            r[j].x = hiT ?  dy : dx;            // *( -i ) on hiT lanes
            r[j].y = hiT ? -dx : dy;
        }
        const float s1v = (l & 1) ? -1.f : 1.f;
        #pragma unroll
        for (int j = 0; j < 16; ++j) {
            float2 v = dpp2<DPP_XOR1>(r[j]);
            r[j].x = fmaf(s1v, r[j].x, v.x);
            r[j].y = fmaf(s1v, r[j].y, v.y);
        }
    }
    #pragma unroll
    for (int j = 0; j < 16; ++j) zz[SLOT(cb + (j << 2))] = r[j];
    __syncthreads();

    // ======== pointwise product in bit-reversed domain (verified R2) ========
    #pragma unroll
    for (int jj = 0; jj < FFT_N / BLOCK; ++jj) {
        int j  = tid + jj * BLOCK;
        int f  = (int)(__brev((unsigned)j) >> (32 - LOGN));
        int fp = (FFT_N - f) & (FFT_N - 1);
        if (f < fp) {
            int jp = (int)(__brev((unsigned)fp) >> (32 - LOGN));
            float2 a = zz[SLOT(j)];
            float2 c = zz[SLOT(jp)];
            float ar = a.x * a.x - a.y * a.y;
            float cr = c.x * c.x - c.y * c.y;
            float xr = ar - cr;
            float xi = 2.f * (a.x * a.y + c.x * c.y);
            zz[SLOT(j)]  = make_float2(0.25f * xi, -0.25f * xr);
            zz[SLOT(jp)] = make_float2(0.25f * xi,  0.25f * xr);
        } else if (f == fp) {
            float2 a = zz[SLOT(j)];
            zz[SLOT(j)] = make_float2(a.x * a.y, 0.f);
        }
    }
    __syncthreads();

    // ======== inv wave-local 1024-pt IFFT on chunk w ========
    #pragma unroll
    for (int j = 0; j < 16; ++j) r[j] = zz[SLOT(cb + (j << 2))];
    // gamma': m=1 then m=2 via DPP
    {
        const float s1v = (l & 1) ? -1.f : 1.f;
        #pragma unroll
        for (int j = 0; j < 16; ++j) {
            float2 v = dpp2<DPP_XOR1>(r[j]);
            r[j].x = fmaf(s1v, r[j].x, v.x);
            r[j].y = fmaf(s1v, r[j].y, v.y);
        }
        const float s2  = (l & 2) ? -1.f : 1.f;
        const bool  hiT = ((l & 3) == 3);   // b-lane with k=1: T = +i applied pre-combine
        #pragma unroll
        for (int j = 0; j < 16; ++j) {
            float2 x = r[j];
            float xr = hiT ? -x.y : x.x;    // *(+i) on hiT lanes
            float xi = hiT ?  x.x : x.y;
            x.x = xr; x.y = xi;
            float2 v = dpp2<DPP_XOR2>(x);
            r[j].x = fmaf(s2, x.x, v.x);
            r[j].y = fmaf(s2, x.y, v.y);
        }
    }
    // beta': m=4..32
    fft16_dit(r, (float)(l & 3) * (3.14159265358979323846f / 32.f));
    #pragma unroll
    for (int j = 0; j < 16; ++j) zz[SLOT(cb + (j << 2))] = r[j];
    __asm__ volatile("s_waitcnt lgkmcnt(0)" ::: "memory");   // wave-private exchange
    // alpha': m=64..512
    #pragma unroll
    for (int j = 0; j < 16; ++j) r[j] = zz[SLOT(W + l + (j << 6))];
    fft16_dit(r, (float)l * (3.14159265358979323846f / 512.f));
    #pragma unroll
    for (int j = 0; j < 16; ++j) zz[SLOT(W + l + (j << 6))] = r[j];
    __syncthreads();

    // ======== inv pass A': m=1024..8192 + fused global store ========
    #pragma unroll
    for (int j = 0; j < 16; ++j) r[j] = zz[SLOT(tid + (j << 10))];
    fft16_dit(r, (float)tid * (3.14159265358979323846f / 8192.f));

    float* outr = out + (size_t)b * FFT_N;
    const float inv_n = 1.0f / (float)FFT_N;
    #pragma unroll
    for (int j = 0; j < 16; ++j) {
        outr[tid + (j << 10)] = r[j].x * inv_n;
    }
}

extern "C" void kernel_launch(void* const* d_in, const int* in_sizes, int n_in,
                              void* d_out, int out_size, void* d_ws, size_t ws_size,
                              hipStream_t stream) {
    const float* x1 = (const float*)d_in[0];
    const float* x2 = (const float*)d_in[1];
    const int*   h1 = (const int*)d_in[2];
    const float* s1 = (const float*)d_in[3];
    float* out = (float*)d_out;
    const int B = in_sizes[0] / DIM;   // 256
    cbp_fft_kernel<<<B, BLOCK, 0, stream>>>(x1, x2, h1, s1, out);
}

// Round 4
// 106.214 us; speedup vs baseline: 1.0344x; 1.0344x over previous
//
#include <hip/hip_runtime.h>

// CompactBilinearPooling: count-sketch + circular conv via FFT (B=256, D=4096, N=16384).
// R4 = R3 + __launch_bounds__(BLOCK, 4). R3's counters showed VGPR_Count=64
// with +22 MB of scratch WRITE traffic: the compiler capped regs at 64
// (8 waves/EU target that LDS=128KB makes impossible) and spilled r[16].
// Declaring 4 waves/EU (our actual residency: one 1024-thread block/CU)
// raises the cap to 128 VGPRs -> no spill.
// Structure (verified R3): pass A (stride 1024) + wave-local 1024-pt FFT
// (alpha regs -> wave-private LDS exchange -> beta regs -> gamma via DPP),
// product in bit-reversed domain, mirrored inverse, fused store.
// LDS: XOR swizzle slot = e ^ ((e>>4)&15), exact 128 KB.

#define FFT_N   16384
#define LOGN    14
#define BLOCK   1024
#define DIM     4096
#define SLOT(e) ((e) ^ (((e) >> 4) & 15))

__device__ __forceinline__ float2 cmul(float2 a, float2 b) {
    return make_float2(a.x * b.x - a.y * b.y, a.x * b.y + a.y * b.x);
}
__device__ __forceinline__ float2 csqr(float2 a) {
    return make_float2(a.x * a.x - a.y * a.y, 2.f * a.x * a.y);
}

template<int CTRL>
__device__ __forceinline__ float2 dpp2(float2 v) {
    float2 o;
    o.x = __int_as_float(__builtin_amdgcn_update_dpp(0, __float_as_int(v.x), CTRL, 0xF, 0xF, false));
    o.y = __int_as_float(__builtin_amdgcn_update_dpp(0, __float_as_int(v.y), CTRL, 0xF, 0xF, false));
    return o;
}
#define DPP_XOR1 0xB1   // quad_perm [1,0,3,2]
#define DPP_XOR2 0x4E   // quad_perm [2,3,0,1]

#define DECL_TW_TABLES \
    const float CT[8] = {1.f, 0.92387953f, 0.70710678f, 0.38268343f, 0.f, -0.38268343f, -0.70710678f, -0.92387953f}; \
    const float ST[8] = {0.f, 0.38268343f, 0.70710678f, 0.92387953f, 1.f, 0.92387953f, 0.70710678f, 0.38268343f};

// Forward DIF, 4 stages over the register index (verified R2/R3).
// Stage p: butterfly twiddle T = W[p] * exp(-i*pi*jp/2^p), W[3]=exp(i*phi).
__device__ __forceinline__ void fft16_dif(float2* r, float phi) {
    DECL_TW_TABLES
    float2 W[4];
    __sincosf(phi, &W[3].y, &W[3].x);
    W[2] = csqr(W[3]); W[1] = csqr(W[2]); W[0] = csqr(W[1]);
    #pragma unroll
    for (int p = 3; p >= 0; --p) {
        #pragma unroll
        for (int h = 0; h < 8; ++h) {
            const int jp = h & ((1 << p) - 1);
            const int j  = ((h >> p) << (p + 1)) | jp;
            const int ci = jp << (3 - p);
            const float2 T = cmul(W[p], make_float2(CT[ci], -ST[ci]));
            float2 a = r[j], b = r[j + (1 << p)];
            r[j] = make_float2(a.x + b.x, a.y + b.y);
            float2 d = make_float2(a.x - b.x, a.y - b.y);
            r[j + (1 << p)] = cmul(d, T);
        }
    }
}

// Inverse DIT, 4 stages (verified R2/R3). T = W[p] * exp(+i*pi*jp/2^p).
__device__ __forceinline__ void fft16_dit(float2* r, float phi) {
    DECL_TW_TABLES
    float2 W[4];
    __sincosf(phi, &W[3].y, &W[3].x);
    W[2] = csqr(W[3]); W[1] = csqr(W[2]); W[0] = csqr(W[1]);
    #pragma unroll
    for (int p = 0; p <= 3; ++p) {
        #pragma unroll
        for (int h = 0; h < 8; ++h) {
            const int jp = h & ((1 << p) - 1);
            const int j  = ((h >> p) << (p + 1)) | jp;
            const int ci = jp << (3 - p);
            const float2 T = cmul(W[p], make_float2(CT[ci], ST[ci]));
            float2 a = r[j];
            float2 b = cmul(r[j + (1 << p)], T);
            r[j]            = make_float2(a.x + b.x, a.y + b.y);
            r[j + (1 << p)] = make_float2(a.x - b.x, a.y - b.y);
        }
    }
}

__launch_bounds__(BLOCK, 4)
__global__ void cbp_fft_kernel(const float* __restrict__ x1,
                               const float* __restrict__ x2,
                               const int* __restrict__ h1,
                               const float* __restrict__ s1,
                               float* __restrict__ out) {
    __shared__ float2 zz[FFT_N];   // 128 KB, XOR-swizzled addressing
    const int tid = threadIdx.x;
    const int l   = tid & 63;     // lane
    const int w   = tid >> 6;     // wave = chunk index
    const int b   = blockIdx.x;

    // ---- zero sketch ----
    #pragma unroll
    for (int j = 0; j < 16; ++j) zz[tid + (j << 10)] = make_float2(0.f, 0.f);
    __syncthreads();

    // ---- count-sketch scatter ----
    const float* x1r = x1 + (size_t)b * DIM;
    const float* x2r = x2 + (size_t)b * DIM;
    #pragma unroll
    for (int i = 0; i < DIM / BLOCK; ++i) {
        int d = tid + i * BLOCK;
        float s = s1[d];
        int   h = h1[d];
        atomicAdd(&zz[SLOT(h)].x, s * x1r[d]);
        atomicAdd(&zz[SLOT(h)].y, s * x2r[d]);
    }
    __syncthreads();

    float2 r[16];
    const int W  = w << 10;                               // chunk base
    const int cb = W + (l & 3) + ((l >> 2) << 6);         // cluster base (Lbeta)

    // ======== fwd pass A: m=8192..1024 (stride 1024, cross-wave) ========
    #pragma unroll
    for (int j = 0; j < 16; ++j) r[j] = zz[SLOT(tid + (j << 10))];
    fft16_dif(r, (float)tid * (-3.14159265358979323846f / 8192.f));
    #pragma unroll
    for (int j = 0; j < 16; ++j) zz[SLOT(tid + (j << 10))] = r[j];
    __syncthreads();

    // ======== fwd wave-local 1024-pt FFT on chunk w ========
    // alpha: m=512..64, layout e = l + j*64
    #pragma unroll
    for (int j = 0; j < 16; ++j) r[j] = zz[SLOT(W + l + (j << 6))];
    fft16_dif(r, (float)l * (-3.14159265358979323846f / 512.f));
    #pragma unroll
    for (int j = 0; j < 16; ++j) zz[SLOT(W + l + (j << 6))] = r[j];
    __asm__ volatile("s_waitcnt lgkmcnt(0)" ::: "memory");   // wave-private exchange
    // beta: m=32..4, layout e = (l&3) + j*4 + (l>>2)*64
    #pragma unroll
    for (int j = 0; j < 16; ++j) r[j] = zz[SLOT(cb + (j << 2))];
    fft16_dif(r, (float)(l & 3) * (-3.14159265358979323846f / 32.f));
    // gamma: m=2 then m=1 via DPP (partner lanes l^2, l^1; e&3 == l&3)
    {
        const float s2  = (l & 2) ? -1.f : 1.f;
        const bool  hiT = ((l & 3) == 3);   // upper lane with k=1: T = -i
        #pragma unroll
        for (int j = 0; j < 16; ++j) {
            float2 v = dpp2<DPP_XOR2>(r[j]);
            float dx = fmaf(s2, r[j].x, v.x);   // lower: a+b ; upper: a-b
            float dy = fmaf(s2, r[j].y, v.y);
            r[j].x = hiT ?  dy : dx;            // *( -i ) on hiT lanes
            r[j].y = hiT ? -dx : dy;
        }
        const float s1v = (l & 1) ? -1.f : 1.f;
        #pragma unroll
        for (int j = 0; j < 16; ++j) {
            float2 v = dpp2<DPP_XOR1>(r[j]);
            r[j].x = fmaf(s1v, r[j].x, v.x);
            r[j].y = fmaf(s1v, r[j].y, v.y);
        }
    }
    #pragma unroll
    for (int j = 0; j < 16; ++j) zz[SLOT(cb + (j << 2))] = r[j];
    __syncthreads();

    // ======== pointwise product in bit-reversed domain (verified R2) ========
    #pragma unroll
    for (int jj = 0; jj < FFT_N / BLOCK; ++jj) {
        int j  = tid + jj * BLOCK;
        int f  = (int)(__brev((unsigned)j) >> (32 - LOGN));
        int fp = (FFT_N - f) & (FFT_N - 1);
        if (f < fp) {
            int jp = (int)(__brev((unsigned)fp) >> (32 - LOGN));
            float2 a = zz[SLOT(j)];
            float2 c = zz[SLOT(jp)];
            float ar = a.x * a.x - a.y * a.y;
            float cr = c.x * c.x - c.y * c.y;
            float xr = ar - cr;
            float xi = 2.f * (a.x * a.y + c.x * c.y);
            zz[SLOT(j)]  = make_float2(0.25f * xi, -0.25f * xr);
            zz[SLOT(jp)] = make_float2(0.25f * xi,  0.25f * xr);
        } else if (f == fp) {
            float2 a = zz[SLOT(j)];
            zz[SLOT(j)] = make_float2(a.x * a.y, 0.f);
        }
    }
    __syncthreads();

    // ======== inv wave-local 1024-pt IFFT on chunk w ========
    #pragma unroll
    for (int j = 0; j < 16; ++j) r[j] = zz[SLOT(cb + (j << 2))];
    // gamma': m=1 then m=2 via DPP
    {
        const float s1v = (l & 1) ? -1.f : 1.f;
        #pragma unroll
        for (int j = 0; j < 16; ++j) {
            float2 v = dpp2<DPP_XOR1>(r[j]);
            r[j].x = fmaf(s1v, r[j].x, v.x);
            r[j].y = fmaf(s1v, r[j].y, v.y);
        }
        const float s2  = (l & 2) ? -1.f : 1.f;
        const bool  hiT = ((l & 3) == 3);   // b-lane with k=1: T = +i applied pre-combine
        #pragma unroll
        for (int j = 0; j < 16; ++j) {
            float2 x = r[j];
            float xr = hiT ? -x.y : x.x;    // *(+i) on hiT lanes
            float xi = hiT ?  x.x : x.y;
            x.x = xr; x.y = xi;
            float2 v = dpp2<DPP_XOR2>(x);
            r[j].x = fmaf(s2, x.x, v.x);
            r[j].y = fmaf(s2, x.y, v.y);
        }
    }
    // beta': m=4..32
    fft16_dit(r, (float)(l & 3) * (3.14159265358979323846f / 32.f));
    #pragma unroll
    for (int j = 0; j < 16; ++j) zz[SLOT(cb + (j << 2))] = r[j];
    __asm__ volatile("s_waitcnt lgkmcnt(0)" ::: "memory");   // wave-private exchange
    // alpha': m=64..512
    #pragma unroll
    for (int j = 0; j < 16; ++j) r[j] = zz[SLOT(W + l + (j << 6))];
    fft16_dit(r, (float)l * (3.14159265358979323846f / 512.f));
    #pragma unroll
    for (int j = 0; j < 16; ++j) zz[SLOT(W + l + (j << 6))] = r[j];
    __syncthreads();

    // ======== inv pass A': m=1024..8192 + fused global store ========
    #pragma unroll
    for (int j = 0; j < 16; ++j) r[j] = zz[SLOT(tid + (j << 10))];
    fft16_dit(r, (float)tid * (3.14159265358979323846f / 8192.f));

    float* outr = out + (size_t)b * FFT_N;
    const float inv_n = 1.0f / (float)FFT_N;
    #pragma unroll
    for (int j = 0; j < 16; ++j) {
        outr[tid + (j << 10)] = r[j].x * inv_n;
    }
}

extern "C" void kernel_launch(void* const* d_in, const int* in_sizes, int n_in,
                              void* d_out, int out_size, void* d_ws, size_t ws_size,
                              hipStream_t stream) {
    const float* x1 = (const float*)d_in[0];
    const float* x2 = (const float*)d_in[1];
    const int*   h1 = (const int*)d_in[2];
    const float* s1 = (const float*)d_in[3];
    float* out = (float*)d_out;
    const int B = in_sizes[0] / DIM;   // 256
    cbp_fft_kernel<<<B, BLOCK, 0, stream>>>(x1, x2, h1, s1, out);
}

// Round 5
// 100.075 us; speedup vs baseline: 1.0978x; 1.0613x over previous
//
#include <hip/hip_runtime.h>

// CompactBilinearPooling: count-sketch + circular conv via FFT (B=256, D=4096, N=16384).
// R5: radix-8 passes, 8 float2 max live per thread. R3/R4 counters proved the
// allocator pins 64 VGPRs (launch_bounds ignored) and round-trips ~88 B/thread
// through scratch/HBM when 16 float2 are live. Fix: 14 stages = 4 radix-8
// passes + 1 radix-4 pass, each pass = two sequential 8-elem sub-groups
// (#pragma unroll 1 so they can't be fused). Live state ~40 VGPRs < 64 cap.
// Fwd P3/P4/P5 and inv P1'/P2'/P3' are wave-private (each wave stays in its
// own 1024-elem span) -> fused with s_waitcnt fence (R3-proven), no barrier.
// LDS: XOR swizzle slot = e ^ ((e>>4)&15), exact 128 KB. Product in
// bit-reversed domain (R2-verified). z = y1 + i*y2 packing (R1-verified).

#define FFT_N   16384
#define LOGN    14
#define BLOCK   1024
#define DIM     4096
#define SLOT(e) ((e) ^ (((e) >> 4) & 15))
#define PI_F    3.14159265358979323846f

__device__ __forceinline__ float2 cmul(float2 a, float2 b) {
    return make_float2(a.x * b.x - a.y * b.y, a.x * b.y + a.y * b.x);
}
__device__ __forceinline__ float2 csqr(float2 a) {
    return make_float2(a.x * a.x - a.y * a.y, 2.f * a.x * a.y);
}

// Radix-8 DIF: 3 stages (reg spans 4,2,1). Elements at base + j*S.
// phi = -pi*k/(4S); stage-p twiddle = W[p]*exp(-i*pi*jp/2^p), W[p]=exp(i*phi*2^(2-p)).
__device__ __forceinline__ void fft8_dif(float2* r, float phi) {
    const float CT8[4] = {1.f, 0.70710678f, 0.f, -0.70710678f};
    const float ST8[4] = {0.f, 0.70710678f, 1.f, 0.70710678f};
    float2 W[3];
    __sincosf(phi, &W[2].y, &W[2].x);
    W[1] = csqr(W[2]); W[0] = csqr(W[1]);
    #pragma unroll
    for (int p = 2; p >= 0; --p) {
        #pragma unroll
        for (int h = 0; h < 4; ++h) {
            const int jp = h & ((1 << p) - 1);
            const int j  = ((h >> p) << (p + 1)) | jp;
            const int ci = jp << (2 - p);
            const float2 T = cmul(W[p], make_float2(CT8[ci], -ST8[ci]));
            float2 a = r[j], b = r[j + (1 << p)];
            r[j] = make_float2(a.x + b.x, a.y + b.y);
            float2 d = make_float2(a.x - b.x, a.y - b.y);
            r[j + (1 << p)] = cmul(d, T);
        }
    }
}

// Radix-8 DIT (inverse): stages p=0,1,2; twiddle sign flipped.
__device__ __forceinline__ void fft8_dit(float2* r, float phi) {
    const float CT8[4] = {1.f, 0.70710678f, 0.f, -0.70710678f};
    const float ST8[4] = {0.f, 0.70710678f, 1.f, 0.70710678f};
    float2 W[3];
    __sincosf(phi, &W[2].y, &W[2].x);
    W[1] = csqr(W[2]); W[0] = csqr(W[1]);
    #pragma unroll
    for (int p = 0; p <= 2; ++p) {
        #pragma unroll
        for (int h = 0; h < 4; ++h) {
            const int jp = h & ((1 << p) - 1);
            const int j  = ((h >> p) << (p + 1)) | jp;
            const int ci = jp << (2 - p);
            const float2 T = cmul(W[p], make_float2(CT8[ci], ST8[ci]));
            float2 a = r[j];
            float2 b = cmul(r[j + (1 << p)], T);
            r[j]            = make_float2(a.x + b.x, a.y + b.y);
            r[j + (1 << p)] = make_float2(a.x - b.x, a.y - b.y);
        }
    }
}

// Radix-4 DIF, stages m=2,1 (k=0, twiddles 1,-i only).
__device__ __forceinline__ void fft4_dif(float2* r) {
    float2 a, b, d;
    a = r[0]; b = r[2]; r[0] = make_float2(a.x + b.x, a.y + b.y);
    r[2] = make_float2(a.x - b.x, a.y - b.y);
    a = r[1]; b = r[3]; r[1] = make_float2(a.x + b.x, a.y + b.y);
    d = make_float2(a.x - b.x, a.y - b.y);
    r[3] = make_float2(d.y, -d.x);                       // * -i
    a = r[0]; b = r[1]; r[0] = make_float2(a.x + b.x, a.y + b.y);
    r[1] = make_float2(a.x - b.x, a.y - b.y);
    a = r[2]; b = r[3]; r[2] = make_float2(a.x + b.x, a.y + b.y);
    r[3] = make_float2(a.x - b.x, a.y - b.y);
}

// Radix-4 DIT (inverse), stages m=1,2.
__device__ __forceinline__ void fft4_dit(float2* r) {
    float2 a, b;
    a = r[0]; b = r[1]; r[0] = make_float2(a.x + b.x, a.y + b.y);
    r[1] = make_float2(a.x - b.x, a.y - b.y);
    a = r[2]; b = r[3]; r[2] = make_float2(a.x + b.x, a.y + b.y);
    r[3] = make_float2(a.x - b.x, a.y - b.y);
    a = r[0]; b = r[2]; r[0] = make_float2(a.x + b.x, a.y + b.y);
    r[2] = make_float2(a.x - b.x, a.y - b.y);
    a = r[1]; b = make_float2(-r[3].y, r[3].x);          // * +i
    r[1] = make_float2(a.x + b.x, a.y + b.y);
    r[3] = make_float2(a.x - b.x, a.y - b.y);
}

__device__ __forceinline__ void pass8_dif(float2* zz, int base, int slog, float phi) {
    float2 r[8];
    #pragma unroll
    for (int j = 0; j < 8; ++j) r[j] = zz[SLOT(base + (j << slog))];
    fft8_dif(r, phi);
    #pragma unroll
    for (int j = 0; j < 8; ++j) zz[SLOT(base + (j << slog))] = r[j];
}
__device__ __forceinline__ void pass8_dit(float2* zz, int base, int slog, float phi) {
    float2 r[8];
    #pragma unroll
    for (int j = 0; j < 8; ++j) r[j] = zz[SLOT(base + (j << slog))];
    fft8_dit(r, phi);
    #pragma unroll
    for (int j = 0; j < 8; ++j) zz[SLOT(base + (j << slog))] = r[j];
}

#define WAVE_FENCE() __asm__ volatile("s_waitcnt lgkmcnt(0)" ::: "memory")

__launch_bounds__(BLOCK, 4)
__global__ void cbp_fft_kernel(const float* __restrict__ x1,
                               const float* __restrict__ x2,
                               const int* __restrict__ h1,
                               const float* __restrict__ s1,
                               float* __restrict__ out) {
    __shared__ float2 zz[FFT_N];   // 128 KB, XOR-swizzled addressing
    const int tid = threadIdx.x;
    const int b   = blockIdx.x;

    // ---- zero sketch ----
    #pragma unroll
    for (int j = 0; j < 16; ++j) zz[tid + (j << 10)] = make_float2(0.f, 0.f);
    __syncthreads();

    // ---- count-sketch scatter ----
    const float* x1r = x1 + (size_t)b * DIM;
    const float* x2r = x2 + (size_t)b * DIM;
    #pragma unroll
    for (int i = 0; i < DIM / BLOCK; ++i) {
        int d = tid + i * BLOCK;
        float s = s1[d];
        int   h = h1[d];
        atomicAdd(&zz[SLOT(h)].x, s * x1r[d]);
        atomicAdd(&zz[SLOT(h)].y, s * x2r[d]);
    }
    __syncthreads();

    // ======== fwd P1: m=8192,4096,2048 (S=2048, one group) ========
    #pragma unroll 1
    for (int q = 0; q < 2; ++q) {
        int k = tid + (q << 10);
        pass8_dif(zz, k, 11, (float)k * (-PI_F / 8192.f));
    }
    __syncthreads();

    // ======== fwd P2: m=1024,512,256 (S=256, 8 groups of 2048) ========
    #pragma unroll 1
    for (int q = 0; q < 2; ++q) {
        int g = tid >> 7;
        int k = (tid & 127) + (q << 7);
        pass8_dif(zz, (g << 11) + k, 8, (float)k * (-PI_F / 1024.f));
    }
    __syncthreads();

    // ======== fwd P3: m=128,64,32 (S=32, 64 groups) — wave-private ========
    #pragma unroll 1
    for (int q = 0; q < 2; ++q) {
        int g = tid >> 4;
        int k = (tid & 15) + (q << 4);
        pass8_dif(zz, (g << 8) + k, 5, (float)k * (-PI_F / 128.f));
    }
    WAVE_FENCE();

    // ======== fwd P4: m=16,8,4 (S=4, 512 groups) — wave-private ========
    #pragma unroll 1
    for (int q = 0; q < 2; ++q) {
        int g = tid >> 1;
        int k = (tid & 1) + (q << 1);
        pass8_dif(zz, (g << 5) + k, 2, (float)k * (-PI_F / 16.f));
    }
    WAVE_FENCE();

    // ======== fwd P5: m=2,1 (radix-4, 4 groups/thread) — wave-private ====
    #pragma unroll 1
    for (int q = 0; q < 4; ++q) {
        int base = (tid << 4) + (q << 2);
        float2 r[4];
        #pragma unroll
        for (int j = 0; j < 4; ++j) r[j] = zz[SLOT(base + j)];
        fft4_dif(r);
        #pragma unroll
        for (int j = 0; j < 4; ++j) zz[SLOT(base + j)] = r[j];
    }
    __syncthreads();

    // ======== pointwise product in bit-reversed domain (R2-verified) ======
    #pragma unroll
    for (int jj = 0; jj < FFT_N / BLOCK; ++jj) {
        int j  = tid + jj * BLOCK;
        int f  = (int)(__brev((unsigned)j) >> (32 - LOGN));
        int fp = (FFT_N - f) & (FFT_N - 1);
        if (f < fp) {
            int jp = (int)(__brev((unsigned)fp) >> (32 - LOGN));
            float2 a = zz[SLOT(j)];
            float2 c = zz[SLOT(jp)];
            float ar = a.x * a.x - a.y * a.y;
            float cr = c.x * c.x - c.y * c.y;
            float xr = ar - cr;
            float xi = 2.f * (a.x * a.y + c.x * c.y);
            zz[SLOT(j)]  = make_float2(0.25f * xi, -0.25f * xr);
            zz[SLOT(jp)] = make_float2(0.25f * xi,  0.25f * xr);
        } else if (f == fp) {
            float2 a = zz[SLOT(j)];
            zz[SLOT(j)] = make_float2(a.x * a.y, 0.f);
        }
    }
    __syncthreads();

    // ======== inv P1': m=1,2 (radix-4) — wave-private ========
    #pragma unroll 1
    for (int q = 0; q < 4; ++q) {
        int base = (tid << 4) + (q << 2);
        float2 r[4];
        #pragma unroll
        for (int j = 0; j < 4; ++j) r[j] = zz[SLOT(base + j)];
        fft4_dit(r);
        #pragma unroll
        for (int j = 0; j < 4; ++j) zz[SLOT(base + j)] = r[j];
    }
    WAVE_FENCE();

    // ======== inv P2': m=4,8,16 (S=4) — wave-private ========
    #pragma unroll 1
    for (int q = 0; q < 2; ++q) {
        int g = tid >> 1;
        int k = (tid & 1) + (q << 1);
        pass8_dit(zz, (g << 5) + k, 2, (float)k * (PI_F / 16.f));
    }
    WAVE_FENCE();

    // ======== inv P3': m=32,64,128 (S=32) — wave-private ========
    #pragma unroll 1
    for (int q = 0; q < 2; ++q) {
        int g = tid >> 4;
        int k = (tid & 15) + (q << 4);
        pass8_dit(zz, (g << 8) + k, 5, (float)k * (PI_F / 128.f));
    }
    __syncthreads();

    // ======== inv P4': m=256,512,1024 (S=256) ========
    #pragma unroll 1
    for (int q = 0; q < 2; ++q) {
        int g = tid >> 7;
        int k = (tid & 127) + (q << 7);
        pass8_dit(zz, (g << 11) + k, 8, (float)k * (PI_F / 1024.f));
    }
    __syncthreads();

    // ======== inv P5': m=2048,4096,8192 (S=2048) + fused global store =====
    float* outr = out + (size_t)b * FFT_N;
    const float inv_n = 1.0f / (float)FFT_N;
    #pragma unroll 1
    for (int q = 0; q < 2; ++q) {
        int k = tid + (q << 10);
        float2 r[8];
        #pragma unroll
        for (int j = 0; j < 8; ++j) r[j] = zz[SLOT(k + (j << 11))];
        fft8_dit(r, (float)k * (PI_F / 8192.f));
        #pragma unroll
        for (int j = 0; j < 8; ++j) outr[k + (j << 11)] = r[j].x * inv_n;
    }
}

extern "C" void kernel_launch(void* const* d_in, const int* in_sizes, int n_in,
                              void* d_out, int out_size, void* d_ws, size_t ws_size,
                              hipStream_t stream) {
    const float* x1 = (const float*)d_in[0];
    const float* x2 = (const float*)d_in[1];
    const int*   h1 = (const int*)d_in[2];
    const float* s1 = (const float*)d_in[3];
    float* out = (float*)d_out;
    const int B = in_sizes[0] / DIM;   // 256
    cbp_fft_kernel<<<B, BLOCK, 0, stream>>>(x1, x2, h1, s1, out);
}

// Round 6
// 95.995 us; speedup vs baseline: 1.1445x; 1.0425x over previous
//
#include <hip/hip_runtime.h>

// CompactBilinearPooling via count-sketch + FFT circular conv (B=256, D=4096, N=16384).
// R6: half-size FFT structure.
//  fwd: c1 = y1_even + i*y1_odd, c2 = y2_even + i*y2_odd -> two independent
//       8192-pt DIF FFTs (threads 0-511 on c1, 512-1023 on c2).
//  pairing: fused rfft-unpack + product + irfft-pretwiddle, one thread owns
//       both positions of each (k, N1-k) pair -> no internal barrier.
//  inv: one 8192-pt DIT IFFT; final radix-2 stage fused with coalesced
//       float4 stores (out[2n]=Re w, out[2n+1]=Im w), scale 1/8192.
// Discipline from R5 counters: never >8 float2 live (VGPR<=64, no scratch).
// LDS: two 8192-float2 arrays, slot(e)=e^((e>>4)&15) within each, 128 KB.

#define N1      8192
#define BLOCK   1024
#define DIM     4096
#define PI_F    3.14159265358979323846f
#define SLOT(e) ((e) ^ (((e) >> 4) & 15))
#define REV13(x) ((int)(__brev((unsigned)(x)) >> 19))
#define WAVE_FENCE() __asm__ volatile("s_waitcnt lgkmcnt(0)" ::: "memory")

__device__ __forceinline__ float2 cmul(float2 a, float2 b) {
    return make_float2(a.x * b.x - a.y * b.y, a.x * b.y + a.y * b.x);
}
__device__ __forceinline__ float2 csqr(float2 a) {
    return make_float2(a.x * a.x - a.y * a.y, 2.f * a.x * a.y);
}
__device__ __forceinline__ float2 cadd(float2 a, float2 b) { return make_float2(a.x + b.x, a.y + b.y); }
__device__ __forceinline__ float2 csub(float2 a, float2 b) { return make_float2(a.x - b.x, a.y - b.y); }

// Radix-8 DIF (R5-verified): covers stages m=4S,2S,S; base=G*8S+k, k<S,
// elements base+j*S, phi = -pi*k/(4S).
__device__ __forceinline__ void fft8_dif(float2* r, float phi) {
    const float CT8[4] = {1.f, 0.70710678f, 0.f, -0.70710678f};
    const float ST8[4] = {0.f, 0.70710678f, 1.f, 0.70710678f};
    float2 W[3];
    __sincosf(phi, &W[2].y, &W[2].x);
    W[1] = csqr(W[2]); W[0] = csqr(W[1]);
    #pragma unroll
    for (int p = 2; p >= 0; --p) {
        #pragma unroll
        for (int h = 0; h < 4; ++h) {
            const int jp = h & ((1 << p) - 1);
            const int j  = ((h >> p) << (p + 1)) | jp;
            const int ci = jp << (2 - p);
            const float2 T = cmul(W[p], make_float2(CT8[ci], -ST8[ci]));
            float2 a = r[j], b = r[j + (1 << p)];
            r[j] = cadd(a, b);
            r[j + (1 << p)] = cmul(csub(a, b), T);
        }
    }
}

// Radix-8 DIT (R5-verified): stages m=S,2S,4S; phi = +pi*k/(4S).
__device__ __forceinline__ void fft8_dit(float2* r, float phi) {
    const float CT8[4] = {1.f, 0.70710678f, 0.f, -0.70710678f};
    const float ST8[4] = {0.f, 0.70710678f, 1.f, 0.70710678f};
    float2 W[3];
    __sincosf(phi, &W[2].y, &W[2].x);
    W[1] = csqr(W[2]); W[0] = csqr(W[1]);
    #pragma unroll
    for (int p = 0; p <= 2; ++p) {
        #pragma unroll
        for (int h = 0; h < 4; ++h) {
            const int jp = h & ((1 << p) - 1);
            const int j  = ((h >> p) << (p + 1)) | jp;
            const int ci = jp << (2 - p);
            const float2 T = cmul(W[p], make_float2(CT8[ci], ST8[ci]));
            float2 a = r[j];
            float2 b = cmul(r[j + (1 << p)], T);
            r[j]            = cadd(a, b);
            r[j + (1 << p)] = csub(a, b);
        }
    }
}

// Radix-4 DIF with twiddle: stages m=2S,S; base=G*4S+k, k<S, phi=-pi*k/(2S).
__device__ __forceinline__ void fft4_dif_tw(float2* r, float phi) {
    float2 W1; __sincosf(phi, &W1.y, &W1.x);
    float2 W0 = csqr(W1);
    float2 a, b;
    a = r[0]; b = r[2]; r[0] = cadd(a, b); r[2] = cmul(csub(a, b), W1);
    a = r[1]; b = r[3]; r[1] = cadd(a, b);
    r[3] = cmul(csub(a, b), make_float2(W1.y, -W1.x));   // W1 * (-i)
    a = r[0]; b = r[1]; r[0] = cadd(a, b); r[1] = cmul(csub(a, b), W0);
    a = r[2]; b = r[3]; r[2] = cadd(a, b); r[3] = cmul(csub(a, b), W0);
}

// Fused rfft-unpack + product + irfft-pretwiddle for one bit-rev position j.
// Reads C1/C2 at j and partner j2; writes z at j and j2. Self-contained per
// thread (each position read/written by exactly one slot).
__device__ __forceinline__ void pair_slot(float2* zz, int j) {
    const int k  = REV13(j);
    const int kp = (N1 - k) & (N1 - 1);
    const int j2 = REV13(kp);
    float2 A = zz[SLOT(j)];
    float2 B = zz[SLOT(j2)];
    float2 C = zz[N1 + SLOT(j)];
    float2 D = zz[N1 + SLOT(j2)];
    // E = (A + conj B)/2 ; O = -(i/2)(A - conj B)
    float2 E  = make_float2(0.5f * (A.x + B.x),  0.5f * (A.y - B.y));
    float2 O  = make_float2(0.5f * (A.y + B.y), -0.5f * (A.x - B.x));
    float2 F  = make_float2(0.5f * (C.x + D.x),  0.5f * (C.y - D.y));
    float2 Ov = make_float2(0.5f * (C.y + D.y), -0.5f * (C.x - D.x));
    float2 Tm; __sincosf(-PI_F * (float)k * (1.f / 8192.f), &Tm.y, &Tm.x); // e^{-i pi k/N1}
    float2 u = cmul(Tm, O);
    float2 v = cmul(Tm, Ov);
    float2 G = cmul(cadd(E, u), cadd(F, v));   // P[k]
    float2 H = cmul(csub(E, u), csub(F, v));   // conj(P[N1-k])
    float2 S  = make_float2(0.5f * (G.x + H.x), 0.5f * (G.y + H.y));
    float2 gh = csub(G, H);
    float2 t2 = cmul(make_float2(Tm.x, -Tm.y), gh);       // conj(Tm)*(G-H)
    float2 Dv = make_float2(-0.5f * t2.y, 0.5f * t2.x);    // (i/2)*conj(Tm)*(G-H)
    zz[SLOT(j)]  = cadd(S, Dv);                            // z[k]
    zz[SLOT(j2)] = make_float2(S.x - Dv.x, -(S.y - Dv.y)); // conj(S - Dv) = z[k']
}

__launch_bounds__(BLOCK, 4)
__global__ void cbp_fft_kernel(const float* __restrict__ x1,
                               const float* __restrict__ x2,
                               const int* __restrict__ h1,
                               const float* __restrict__ s1,
                               float* __restrict__ out) {
    __shared__ float2 zz[2 * N1];   // c1 | c2, 128 KB
    const int tid = threadIdx.x;
    const int b   = blockIdx.x;
    float* zf = (float*)zz;

    // ---- zero both sketches ----
    #pragma unroll
    for (int j = 0; j < 16; ++j) zz[tid + (j << 10)] = make_float2(0.f, 0.f);
    __syncthreads();

    // ---- count-sketch scatter: y[h] += s*x  ->  c[h>>1].{x,y} by parity ----
    const float* x1r = x1 + (size_t)b * DIM;
    const float* x2r = x2 + (size_t)b * DIM;
    #pragma unroll
    for (int i = 0; i < DIM / BLOCK; ++i) {
        int d = tid + (i << 10);
        float s = s1[d];
        int   h = h1[d];
        int  fi = (SLOT(h >> 1) << 1) | (h & 1);
        atomicAdd(&zf[fi], s * x1r[d]);
        atomicAdd(&zf[2 * N1 + fi], s * x2r[d]);
    }
    __syncthreads();

    // ======== forward: two independent 8192-pt DIF FFTs ========
    const int half = tid >> 9;          // 0 -> c1 (waves 0-7), 1 -> c2 (waves 8-15)
    const int tt   = tid & 511;
    float2* A = zz + half * N1;

    // P1: S=1024 (cross-wave within half)
    #pragma unroll 1
    for (int q = 0; q < 2; ++q) {
        int k = tt + (q << 9);
        float2 r[8];
        #pragma unroll
        for (int j = 0; j < 8; ++j) r[j] = A[SLOT(k + (j << 10))];
        fft8_dif(r, (float)k * (-PI_F / 4096.f));
        #pragma unroll
        for (int j = 0; j < 8; ++j) A[SLOT(k + (j << 10))] = r[j];
    }
    __syncthreads();

    // P2: S=128, group 1024 = 1 wave  — wave-private
    #pragma unroll 1
    for (int q = 0; q < 2; ++q) {
        int g = tt >> 6;
        int k = (tt & 63) + (q << 6);
        int base = (g << 10) + k;
        float2 r[8];
        #pragma unroll
        for (int j = 0; j < 8; ++j) r[j] = A[SLOT(base + (j << 7))];
        fft8_dif(r, (float)k * (-PI_F / 512.f));
        #pragma unroll
        for (int j = 0; j < 8; ++j) A[SLOT(base + (j << 7))] = r[j];
    }
    WAVE_FENCE();

    // P3: S=16, group 128 = 8 threads — wave-private
    #pragma unroll 1
    for (int q = 0; q < 2; ++q) {
        int g = tt >> 3;
        int k = (tt & 7) + (q << 3);
        int base = (g << 7) + k;
        float2 r[8];
        #pragma unroll
        for (int j = 0; j < 8; ++j) r[j] = A[SLOT(base + (j << 4))];
        fft8_dif(r, (float)k * (-PI_F / 64.f));
        #pragma unroll
        for (int j = 0; j < 8; ++j) A[SLOT(base + (j << 4))] = r[j];
    }
    WAVE_FENCE();

    // P4: radix-4, S=4, group 16 = 1 thread — thread-private
    #pragma unroll 1
    for (int k = 0; k < 4; ++k) {
        int base = (tt << 4) + k;
        float2 r[4];
        #pragma unroll
        for (int j = 0; j < 4; ++j) r[j] = A[SLOT(base + (j << 2))];
        fft4_dif_tw(r, (float)k * (-PI_F / 8.f));
        #pragma unroll
        for (int j = 0; j < 4; ++j) A[SLOT(base + (j << 2))] = r[j];
    }
    WAVE_FENCE();

    // P5: radix-4, S=1 (k=0) — thread-private
    #pragma unroll 1
    for (int q = 0; q < 4; ++q) {
        int base = (tt << 4) + (q << 2);
        float2 r[4];
        #pragma unroll
        for (int j = 0; j < 4; ++j) r[j] = A[SLOT(base + j)];
        fft4_dif_tw(r, 0.f);
        #pragma unroll
        for (int j = 0; j < 4; ++j) A[SLOT(base + j)] = r[j];
    }
    __syncthreads();

    // ======== fused pairing: unpack + product + irfft pre-twiddle ========
    // even bit-rev positions j <-> k in [0, 4096); each slot owns {j, j2}.
    #pragma unroll 1
    for (int i = 0; i < 4; ++i) {
        int j = (tid + (i << 10)) << 1;
        pair_slot(zz, j);
    }
    if (tid == 0) pair_slot(zz, 1);   // k = 4096 (Nyquist of half), j = rev13(4096) = 1
    __syncthreads();

    // ======== inverse: one 8192-pt DIT IFFT on c1 region ========
    // P1': S=1, group 8 = 1 thread
    {
        int base = tid << 3;
        float2 r[8];
        #pragma unroll
        for (int j = 0; j < 8; ++j) r[j] = zz[SLOT(base + j)];
        fft8_dit(r, 0.f);
        #pragma unroll
        for (int j = 0; j < 8; ++j) zz[SLOT(base + j)] = r[j];
    }
    WAVE_FENCE();
    // P2': S=8, group 64 = 8 threads — wave-private
    {
        int g = tid >> 3, k = tid & 7;
        int base = (g << 6) + k;
        float2 r[8];
        #pragma unroll
        for (int j = 0; j < 8; ++j) r[j] = zz[SLOT(base + (j << 3))];
        fft8_dit(r, (float)k * (PI_F / 32.f));
        #pragma unroll
        for (int j = 0; j < 8; ++j) zz[SLOT(base + (j << 3))] = r[j];
    }
    WAVE_FENCE();
    // P3': S=64, group 512 = 1 wave — wave-private
    {
        int g = tid >> 6, k = tid & 63;
        int base = (g << 9) + k;
        float2 r[8];
        #pragma unroll
        for (int j = 0; j < 8; ++j) r[j] = zz[SLOT(base + (j << 6))];
        fft8_dit(r, (float)k * (PI_F / 256.f));
        #pragma unroll
        for (int j = 0; j < 8; ++j) zz[SLOT(base + (j << 6))] = r[j];
    }
    __syncthreads();
    // P4': S=512, group 4096 = 8 waves — barrier-bounded
    {
        int g = tid >> 9, k = tid & 511;
        int base = (g << 12) + k;
        float2 r[8];
        #pragma unroll
        for (int j = 0; j < 8; ++j) r[j] = zz[SLOT(base + (j << 9))];
        fft8_dit(r, (float)k * (PI_F / 2048.f));
        #pragma unroll
        for (int j = 0; j < 8; ++j) zz[SLOT(base + (j << 9))] = r[j];
    }
    __syncthreads();

    // P5': radix-2, S=4096, fused with coalesced float4 stores.
    // w[n] = a + T*b, w[n+4096] = a - T*b, T = e^{+i pi n/4096};
    // out[2n] = Re w / N1, out[2n+1] = Im w / N1.
    float* outr = out + (size_t)b * (2 * N1);
    const float inv_n1 = 1.0f / (float)N1;
    #pragma unroll 1
    for (int i = 0; i < 2; ++i) {
        float2 lo[2], hi[2];
        #pragma unroll
        for (int s = 0; s < 2; ++s) {
            int n = (tid << 2) + (i << 1) + s;
            float2 a  = zz[SLOT(n)];
            float2 bb = zz[SLOT(n + 4096)];
            float2 T; __sincosf(PI_F * (float)n * (1.f / 4096.f), &T.y, &T.x);
            float2 tb = cmul(T, bb);
            lo[s] = cadd(a, tb);
            hi[s] = csub(a, tb);
        }
        float4 vlo = make_float4(lo[0].x * inv_n1, lo[0].y * inv_n1,
                                 lo[1].x * inv_n1, lo[1].y * inv_n1);
        float4 vhi = make_float4(hi[0].x * inv_n1, hi[0].y * inv_n1,
                                 hi[1].x * inv_n1, hi[1].y * inv_n1);
        *(float4*)(outr + (tid << 3) + (i << 2)) = vlo;
        *(float4*)(outr + N1 + (tid << 3) + (i << 2)) = vhi;
    }
}

extern "C" void kernel_launch(void* const* d_in, const int* in_sizes, int n_in,
                              void* d_out, int out_size, void* d_ws, size_t ws_size,
                              hipStream_t stream) {
    const float* x1 = (const float*)d_in[0];
    const float* x2 = (const float*)d_in[1];
    const int*   h1 = (const int*)d_in[2];
    const float* s1 = (const float*)d_in[3];
    float* out = (float*)d_out;
    const int B = in_sizes[0] / DIM;   // 256
    cbp_fft_kernel<<<B, BLOCK, 0, stream>>>(x1, x2, h1, s1, out);
}

// Round 8
// 93.727 us; speedup vs baseline: 1.1722x; 1.0242x over previous
//
#include <hip/hip_runtime.h>

// CompactBilinearPooling via count-sketch + FFT circular conv (B=256, D=4096, N=16384).
// R8 = R7 with the P5' addressing bug fixed (b5 ^ d5, NOT b5 + d5 — the XOR
// mask's low bits collide with d5; verified tid=5,d=3: SLOT(23)=22=b5^3).
// Structure (R6-verified algorithm): two 8192 fwd FFTs via even/odd packing,
// fused unpack+product+pretwiddle pairing, one 8192 inverse + fused radix-2
// store. R7 optimizations kept: hoisted swizzle bases (algebraically ==
// SLOT(e), re-audited per pass), conflict-free lane assignment for P3/P4/P5,
// trivial-twiddle specialization, v_pk_fma-friendly v2 math.
// 8-live float2 discipline (R5-proven): VGPR<=64, no scratch spill.

typedef float v2 __attribute__((ext_vector_type(2)));

#define N1      8192
#define BLOCK   1024
#define DIM     4096
#define PI_F    3.14159265358979323846f
#define RS2     0.70710678118654752f
#define SLOT(e) ((e) ^ (((e) >> 4) & 15))
#define REV13(x) ((int)(__brev((unsigned)(x)) >> 19))
#define WAVE_FENCE() __asm__ volatile("s_waitcnt lgkmcnt(0)" ::: "memory")

static __device__ __forceinline__ v2 cmul(v2 a, v2 b) {
    return a.xx * b + (v2){-a.y, a.y} * b.yx;
}
static __device__ __forceinline__ v2 csqr(v2 a) { return cmul(a, a); }
static __device__ __forceinline__ v2 expi(float phi) {
    float s, c; __sincosf(phi, &s, &c); return (v2){c, s};
}

// Radix-8 DIF (stages 4S,2S,S), r[j] at base+j*S, phi = -pi*k/(4S).
static __device__ __forceinline__ void fft8_dif(v2* r, float phi) {
    v2 W2 = expi(phi), W1 = csqr(W2), W0 = csqr(W1);
    v2 W[3] = {W0, W1, W2};
    #pragma unroll
    for (int p = 2; p >= 0; --p) {
        #pragma unroll
        for (int h = 0; h < 4; ++h) {
            const int jp = h & ((1 << p) - 1);
            const int j  = ((h >> p) << (p + 1)) | jp;
            const int ci = jp << (2 - p);
            v2 Wp = W[p], T;
            if (ci == 0)      T = Wp;
            else if (ci == 2) T = (v2){Wp.y, -Wp.x};            // * (0,-1)
            else if (ci == 1) T = cmul(Wp, (v2){RS2, -RS2});
            else              T = cmul(Wp, (v2){-RS2, -RS2});   // ci==3
            v2 a = r[j], bb = r[j + (1 << p)];
            r[j] = a + bb;
            r[j + (1 << p)] = cmul(a - bb, T);
        }
    }
}

// Radix-8 DIT (stages S,2S,4S), phi = +pi*k/(4S).
static __device__ __forceinline__ void fft8_dit(v2* r, float phi) {
    v2 W2 = expi(phi), W1 = csqr(W2), W0 = csqr(W1);
    v2 W[3] = {W0, W1, W2};
    #pragma unroll
    for (int p = 0; p <= 2; ++p) {
        #pragma unroll
        for (int h = 0; h < 4; ++h) {
            const int jp = h & ((1 << p) - 1);
            const int j  = ((h >> p) << (p + 1)) | jp;
            const int ci = jp << (2 - p);
            v2 Wp = W[p], T;
            if (ci == 0)      T = Wp;
            else if (ci == 2) T = (v2){-Wp.y, Wp.x};            // * (0,1)
            else if (ci == 1) T = cmul(Wp, (v2){RS2, RS2});
            else              T = cmul(Wp, (v2){-RS2, RS2});
            v2 a = r[j], bb = cmul(r[j + (1 << p)], T);
            r[j]            = a + bb;
            r[j + (1 << p)] = a - bb;
        }
    }
}

// Radix-8 DIT with k=0 (W=1): pure-constant twiddles.
static __device__ __forceinline__ void fft8_dit0(v2* r) {
    #pragma unroll
    for (int p = 0; p <= 2; ++p) {
        #pragma unroll
        for (int h = 0; h < 4; ++h) {
            const int jp = h & ((1 << p) - 1);
            const int j  = ((h >> p) << (p + 1)) | jp;
            const int ci = jp << (2 - p);
            v2 x = r[j + (1 << p)], bb;
            if (ci == 0)      bb = x;
            else if (ci == 2) bb = (v2){-x.y, x.x};
            else if (ci == 1) bb = cmul(x, (v2){RS2, RS2});
            else              bb = cmul(x, (v2){-RS2, RS2});
            v2 a = r[j];
            r[j] = a + bb; r[j + (1 << p)] = a - bb;
        }
    }
}

// Radix-4 DIF (stages 2S,S) with given W1 = e^{-i pi k/(2S)}.
static __device__ __forceinline__ void fft4_difW(v2* r, v2 W1) {
    v2 W0 = csqr(W1);
    v2 a, bb;
    a = r[0]; bb = r[2]; r[0] = a + bb; r[2] = cmul(a - bb, W1);
    a = r[1]; bb = r[3]; r[1] = a + bb;
    { v2 d = a - bb; r[3] = cmul(d, (v2){W1.y, -W1.x}); }       // W1*(-i)
    a = r[0]; bb = r[1]; r[0] = a + bb; r[1] = cmul(a - bb, W0);
    a = r[2]; bb = r[3]; r[2] = a + bb; r[3] = cmul(a - bb, W0);
}
// Radix-4 DIF, k = 0 (no twiddles).
static __device__ __forceinline__ void fft4_dif0(v2* r) {
    v2 a, bb;
    a = r[0]; bb = r[2]; r[0] = a + bb; r[2] = a - bb;
    a = r[1]; bb = r[3]; r[1] = a + bb;
    { v2 d = a - bb; r[3] = (v2){d.y, -d.x}; }
    a = r[0]; bb = r[1]; r[0] = a + bb; r[1] = a - bb;
    a = r[2]; bb = r[3]; r[2] = a + bb; r[3] = a - bb;
}

// Fused rfft-unpack + product + irfft-pretwiddle (R6-verified formulas).
static __device__ __forceinline__ void pair_slot(v2* zz, int j) {
    const int k  = REV13(j);
    const int kp = (N1 - k) & (N1 - 1);
    const int j2 = REV13(kp);
    v2 A = zz[SLOT(j)], B = zz[SLOT(j2)];
    v2 C = zz[N1 + SLOT(j)], D = zz[N1 + SLOT(j2)];
    v2 E  = (v2){0.5f * (A.x + B.x),  0.5f * (A.y - B.y)};
    v2 O  = (v2){0.5f * (A.y + B.y), -0.5f * (A.x - B.x)};
    v2 F  = (v2){0.5f * (C.x + D.x),  0.5f * (C.y - D.y)};
    v2 Ov = (v2){0.5f * (C.y + D.y), -0.5f * (C.x - D.x)};
    v2 Tm = expi(-PI_F * (float)k * (1.f / 8192.f));
    v2 u = cmul(Tm, O), v = cmul(Tm, Ov);
    v2 G = cmul(E + u, F + v);
    v2 H = cmul(E - u, F - v);
    v2 S  = (v2){0.5f * (G.x + H.x), 0.5f * (G.y + H.y)};
    v2 gh = G - H;
    v2 t2 = cmul((v2){Tm.x, -Tm.y}, gh);
    v2 Dv = (v2){-0.5f * t2.y, 0.5f * t2.x};
    zz[SLOT(j)]  = S + Dv;
    zz[SLOT(j2)] = (v2){S.x - Dv.x, -(S.y - Dv.y)};
}

__launch_bounds__(BLOCK, 4)
__global__ void cbp_fft_kernel(const float* __restrict__ x1,
                               const float* __restrict__ x2,
                               const int* __restrict__ h1,
                               const float* __restrict__ s1,
                               float* __restrict__ out) {
    __shared__ v2 zz[2 * N1];   // c1 | c2, 128 KB
    const int tid = threadIdx.x;
    const int l   = tid & 63;
    const int b   = blockIdx.x;
    float* zf = (float*)zz;

    // ---- zero both sketches ----
    #pragma unroll
    for (int j = 0; j < 16; ++j) zz[tid + (j << 10)] = (v2){0.f, 0.f};
    __syncthreads();

    // ---- count-sketch scatter (random buckets: full SLOT) ----
    const float* x1r = x1 + (size_t)b * DIM;
    const float* x2r = x2 + (size_t)b * DIM;
    #pragma unroll
    for (int i = 0; i < DIM / BLOCK; ++i) {
        int d = tid + (i << 10);
        float s = s1[d];
        int   h = h1[d];
        int  fi = (SLOT(h >> 1) << 1) | (h & 1);
        atomicAdd(&zf[fi], s * x1r[d]);
        atomicAdd(&zf[2 * N1 + fi], s * x2r[d]);
    }
    __syncthreads();

    // ======== forward: two independent 8192-pt DIF FFTs ========
    const int half = tid >> 9;
    const int tt   = tid & 511;
    const int hw   = tt >> 6;        // half-wave index 0..7
    v2* Ah = zz + half * N1;

    // P1 (S=1024): slot(k + j*1024) = (k ^ ((k>>4)&15)) + j*1024
    #pragma unroll 1
    for (int q = 0; q < 2; ++q) {
        int k  = tt + (q << 9);
        int bs = k ^ ((k >> 4) & 15);
        v2 r[8];
        #pragma unroll
        for (int j = 0; j < 8; ++j) r[j] = Ah[bs + (j << 10)];
        fft8_dif(r, (float)k * (-PI_F / 4096.f));
        #pragma unroll
        for (int j = 0; j < 8; ++j) Ah[bs + (j << 10)] = r[j];
    }
    __syncthreads();

    // P2 (S=128, wave-private): slot = (bE ^ 8*(j&1)) + 128j
    #pragma unroll 1
    for (int q = 0; q < 2; ++q) {
        int kk = (tt & 63) + (q << 6);
        int bE = ((hw << 10) + kk) ^ (kk >> 4);
        int bO = bE ^ 8;
        v2 r[8];
        #pragma unroll
        for (int j = 0; j < 8; ++j) r[j] = Ah[((j & 1) ? bO : bE) + (j << 7)];
        fft8_dif(r, (float)kk * (-PI_F / 512.f));
        #pragma unroll
        for (int j = 0; j < 8; ++j) Ah[((j & 1) ? bO : bE) + (j << 7)] = r[j];
    }
    WAVE_FENCE();

    // P3 (S=16, wave-private, conflict-free): slot = (a0 ^ j) + 16j
    #pragma unroll 1
    for (int q = 0; q < 2; ++q) {
        int g  = (hw << 3) + ((l >> 4) << 1) + q;
        int kf = l & 15;
        int a0 = (g << 7) + (kf ^ (q << 3));
        v2 r[8];
        #pragma unroll
        for (int j = 0; j < 8; ++j) r[j] = Ah[(a0 ^ j) + (j << 4)];
        fft8_dif(r, (float)kf * (-PI_F / 64.f));
        #pragma unroll
        for (int j = 0; j < 8; ++j) Ah[(a0 ^ j) + (j << 4)] = r[j];
    }
    WAVE_FENCE();

    // P4/P5 on thread-private 16-span: slot(span*16+i) = sbase ^ i
    {
        const int span  = (hw << 6) + (l & 15) + ((l >> 4) << 4);
        const int sbase = (span << 4) + (span & 15);
        // P4: radix-4 stride 4, W1 = e^{-i pi k4/8} via selects
        #pragma unroll 1
        for (int k4 = 0; k4 < 4; ++k4) {
            float c = (k4 & 1) ? ((k4 & 2) ? 0.38268343f : 0.92387953f)
                               : ((k4 & 2) ? 0.70710678f : 1.f);
            float s = (k4 & 1) ? ((k4 & 2) ? -0.92387953f : -0.38268343f)
                               : ((k4 & 2) ? -0.70710678f : 0.f);
            int sb = sbase ^ k4;
            v2 r[4];
            #pragma unroll
            for (int j = 0; j < 4; ++j) r[j] = Ah[sb ^ (j << 2)];
            fft4_difW(r, (v2){c, s});
            #pragma unroll
            for (int j = 0; j < 4; ++j) Ah[sb ^ (j << 2)] = r[j];
        }
        WAVE_FENCE();
        // P5: radix-4 stride 1, no twiddle
        #pragma unroll 1
        for (int q = 0; q < 4; ++q) {
            int sb = sbase ^ (q << 2);
            v2 r[4];
            #pragma unroll
            for (int j = 0; j < 4; ++j) r[j] = Ah[sb ^ j];
            fft4_dif0(r);
            #pragma unroll
            for (int j = 0; j < 4; ++j) Ah[sb ^ j] = r[j];
        }
    }
    __syncthreads();

    // ======== fused pairing (R6-verified) ========
    #pragma unroll 1
    for (int i = 0; i < 4; ++i) pair_slot(zz, (tid + (i << 10)) << 1);
    if (tid == 0) pair_slot(zz, 1);   // k = 4096 self-pair position
    __syncthreads();

    // ======== inverse: one 8192-pt DIT IFFT ========
    // P1' (S=1, thread-private 8-span): slot(tid*8+i) = B1 ^ i
    {
        int B1 = (tid << 3) ^ ((tid >> 1) & 15);
        v2 r[8];
        #pragma unroll
        for (int i = 0; i < 8; ++i) r[i] = zz[B1 ^ i];
        fft8_dit0(r);
        #pragma unroll
        for (int i = 0; i < 8; ++i) zz[B1 ^ i] = r[i];
    }
    WAVE_FENCE();
    // P2' (S=8, wave-private) — full SLOT
    {
        int g = tid >> 3, k = tid & 7;
        int base = (g << 6) + k;
        v2 r[8];
        #pragma unroll
        for (int j = 0; j < 8; ++j) r[j] = zz[SLOT(base + (j << 3))];
        fft8_dit(r, (float)k * (PI_F / 32.f));
        #pragma unroll
        for (int j = 0; j < 8; ++j) zz[SLOT(base + (j << 3))] = r[j];
    }
    WAVE_FENCE();
    // P3' (S=64, wave-private): 4 bases + 64j immediates
    {
        int k = tid & 63;
        int base0 = ((tid >> 6) << 9) + (k & ~15);
        int Kh = k >> 4, K15 = k & 15;
        int B0  = base0 + (K15 ^ Kh);
        int Bm1 = base0 + (K15 ^ (Kh + 4));
        int Bm2 = base0 + (K15 ^ (Kh + 8));
        int Bm3 = base0 + (K15 ^ (Kh + 12));
        v2 r[8];
        r[0] = zz[B0];        r[1] = zz[Bm1 + 64];
        r[2] = zz[Bm2 + 128]; r[3] = zz[Bm3 + 192];
        r[4] = zz[B0 + 256];  r[5] = zz[Bm1 + 320];
        r[6] = zz[Bm2 + 384]; r[7] = zz[Bm3 + 448];
        fft8_dit(r, (float)k * (PI_F / 256.f));
        zz[B0]        = r[0]; zz[Bm1 + 64]  = r[1];
        zz[Bm2 + 128] = r[2]; zz[Bm3 + 192] = r[3];
        zz[B0 + 256]  = r[4]; zz[Bm1 + 320] = r[5];
        zz[Bm2 + 384] = r[6]; zz[Bm3 + 448] = r[7];
    }
    __syncthreads();
    // P4' (S=512): slot = ((g*4096+k) ^ ((k>>4)&15)) + 512j
    {
        int g = tid >> 9, k = tid & 511;
        int bp = ((g << 12) + k) ^ ((k >> 4) & 15);
        v2 r[8];
        #pragma unroll
        for (int j = 0; j < 8; ++j) r[j] = zz[bp + (j << 9)];
        fft8_dit(r, (float)k * (PI_F / 2048.f));
        #pragma unroll
        for (int j = 0; j < 8; ++j) zz[bp + (j << 9)] = r[j];
    }
    __syncthreads();

    // P5': final radix-2 + coalesced float4 stores.
    // slot(tid*4+d) = b5 ^ d  (XOR! mask low bits collide with d);
    // slot(n+4096) = slot(n) + 4096.
    float* outr = out + (size_t)b * (2 * N1);
    const float inv_n1 = 1.0f / (float)N1;
    const int b5 = (tid << 2) ^ ((tid >> 2) & 15);
    #pragma unroll 1
    for (int i = 0; i < 2; ++i) {
        v2 lo[2], hi[2];
        #pragma unroll
        for (int s2 = 0; s2 < 2; ++s2) {
            int d5 = (i << 1) + s2;
            int n  = (tid << 2) + d5;
            v2 a  = zz[b5 ^ d5];
            v2 bb = zz[(b5 ^ d5) + 4096];
            v2 T  = expi(PI_F * (float)n * (1.f / 4096.f));
            v2 tb = cmul(T, bb);
            lo[s2] = a + tb;
            hi[s2] = a - tb;
        }
        float4 vlo = make_float4(lo[0].x * inv_n1, lo[0].y * inv_n1,
                                 lo[1].x * inv_n1, lo[1].y * inv_n1);
        float4 vhi = make_float4(hi[0].x * inv_n1, hi[0].y * inv_n1,
                                 hi[1].x * inv_n1, hi[1].y * inv_n1);
        *(float4*)(outr + (tid << 3) + (i << 2)) = vlo;
        *(float4*)(outr + N1 + (tid << 3) + (i << 2)) = vhi;
    }
}

extern "C" void kernel_launch(void* const* d_in, const int* in_sizes, int n_in,
                              void* d_out, int out_size, void* d_ws, size_t ws_size,
                              hipStream_t stream) {
    const float* x1 = (const float*)d_in[0];
    const float* x2 = (const float*)d_in[1];
    const int*   h1 = (const int*)d_in[2];
    const float* s1 = (const float*)d_in[3];
    float* out = (float*)d_out;
    const int B = in_sizes[0] / DIM;   // 256
    cbp_fft_kernel<<<B, BLOCK, 0, stream>>>(x1, x2, h1, s1, out);
}